// Round 3
// baseline (3328.497 us; speedup 1.0000x reference)
//
#include <hip/hip_runtime.h>
#include <cstdint>

// ---------------- problem constants ----------------
#define NYD   256
#define NXD   256
#define PADC  22            // PML + FD_PAD
#define NYP_  300           // NY + 2*PAD
#define NXP_  300
#define GD    4             // zero guard ring width (covers radius-4 dependency)
#define ST    308           // padded stride = NYP_ + 2*GD
#define NTT   250
#define NSHOT_ 2
#define NSRC_  8
#define NREC_  64
#define DT_   0.0005f
#define NCELL (NYP_ * NXP_)   // 90000
#define NTHR  512
#define NBLK  ((NCELL + NTHR - 1) / NTHR)   // 176  (<=256 CUs -> all co-resident)

// ---------------- zero workspace ----------------
__global__ void zero_kernel(float* __restrict__ p, long n) {
    long i = (long)blockIdx.x * blockDim.x + threadIdx.x;
    long stride = (long)gridDim.x * blockDim.x;
    for (; i < n; i += stride) p[i] = 0.0f;
}

// ---------------- one-time setup: v2dt2, PML profiles, src/rec masks ----------------
__global__ void populate_kernel(const float* __restrict__ v,
                                const int* __restrict__ srcloc,
                                const int* __restrict__ recloc,
                                float* __restrict__ v2dt2,
                                float* __restrict__ prof,   // [2*ST]: a (guarded), b (guarded)
                                unsigned* __restrict__ srcmask,
                                unsigned long long* __restrict__ recmask) {
    const long f = (long)ST * ST;
    int i = blockIdx.x * 256 + threadIdx.x;

    if (i < NYP_ * NXP_) {
        int y = i / NXP_, x = i % NXP_;
        int vy = min(max(y - PADC, 0), NYD - 1);
        int vx = min(max(x - PADC, 0), NXD - 1);
        float vv = v[vy * NXD + vx];
        v2dt2[(y + GD) * ST + (x + GD)] = vv * vv * (DT_ * DT_);
    }

    if (i < NYP_) {  // DY == DX and NYP == NXP: one profile pair serves both axes
        float fi = (float)i;
        float d = fmaxf(22.0f - fi, fi - 277.0f);
        float frac = fminf(fmaxf(d * (1.0f / 20.0f), 0.0f), 1.0f);
        float sigma_max = 3.0f * 4000.0f * logf(1000.0f) / (2.0f * 20.0f * 5.0f);
        float sigma = sigma_max * frac * frac;
        float alpha = 3.14159265358979323846f * 25.0f * (1.0f - frac);
        float b = expf(-(sigma + alpha) * DT_);
        float a = sigma / (sigma + alpha + 1e-9f) * (b - 1.0f);
        prof[GD + i] = a;        // guard entries stay 0 from zero_kernel
        prof[ST + GD + i] = b;
    }

    if (i < NSHOT_ * NSRC_) {
        int sy = srcloc[2 * i] + PADC;
        int sx = srcloc[2 * i + 1] + PADC;
        int shot = i / NSRC_;
        int s = i % NSRC_;
        atomicOr(&srcmask[shot * f + (long)(sy + GD) * ST + (sx + GD)], 1u << s);
    }

    if (i >= 1024 && i < 1024 + NSHOT_ * NREC_) {
        int j = i - 1024;
        int ry = recloc[2 * j] + PADC;
        int rx = recloc[2 * j + 1] + PADC;
        int shot = j / NREC_;
        int r = j % NREC_;
        atomicOr(&recmask[shot * f + (long)(ry + GD) * ST + (rx + GD)], 1ull << r);
    }
}

// ---------------- software grid barrier ----------------
// Monotonic arrival counter + generation flag; device-scope atomics reach the
// coherent point (works cross-XCD); __threadfence() = release/acquire
// (buffer_wbl2/inv sc1) so normal loads after the barrier see fresh data.
__device__ __forceinline__ void grid_barrier(unsigned* cnt, unsigned* gen,
                                             unsigned target) {
    __syncthreads();
    if (threadIdx.x == 0) {
        __threadfence();                               // release my block's stores
        unsigned arrived = atomicAdd(cnt, 1u) + 1u;
        if (arrived == (unsigned)NBLK * target) {
            atomicAdd(gen, 1u);                        // last arriver opens the gate
        } else {
            while (atomicAdd(gen, 0u) < target) __builtin_amdgcn_s_sleep(1);
        }
        __threadfence();                               // acquire others' stores
    }
    __syncthreads();
}

// ---------------- persistent time loop ----------------
// One thread per cell, both shots looped per thread. Halo recompute (radius 4
// in wfc) removes the intra-step psi dependency so one barrier per step
// suffices. Time-invariant coefficients live in registers across all 250 steps.
__global__ __launch_bounds__(512, 2) void wave_persistent(
    float* __restrict__ wf0, float* __restrict__ wf1,
    float* __restrict__ psiy0, float* __restrict__ psiy1,
    float* __restrict__ psix0, float* __restrict__ psix1,
    float* __restrict__ zetay_b, float* __restrict__ zetax_b,
    const float* __restrict__ v2dt2, const float* __restrict__ prof,
    const unsigned* __restrict__ srcmask,
    const unsigned long long* __restrict__ recmask,
    const float* __restrict__ amps,    // [NSHOT][NSRC][NT]
    float* __restrict__ out,           // [NSHOT][NREC][NT]
    unsigned* bar)                     // [0]=count (monotonic), [32]=gen
{
    unsigned* bcnt = bar;
    unsigned* bgen = bar + 32;   // separate cacheline

    const int gid = blockIdx.x * NTHR + threadIdx.x;
    const bool active = gid < NCELL;
    const int g = active ? gid : 0;
    const int y = g / NXP_, x = g % NXP_;
    const int c = (y + GD) * ST + (x + GD);
    const long f = (long)ST * ST;

    // ---- time-invariant per-cell state, loaded once ----
    const float vd = v2dt2[c];
    const unsigned sm0 = srcmask[c], sm1 = srcmask[f + c];
    const unsigned long long rm0 = recmask[c], rm1 = recmask[f + c];
    float ayh[5], byh[5], axh[5], bxh[5];
#pragma unroll
    for (int j = 0; j < 5; j++) {
        ayh[j] = prof[GD + y + j - 2];
        byh[j] = prof[ST + GD + y + j - 2];
        axh[j] = prof[GD + x + j - 2];
        bxh[j] = prof[ST + GD + x + j - 2];
    }

    const float inv_h  = 0.2f;    // 1/DY
    const float inv_h2 = 0.04f;   // 1/DY^2
    const float C1A = 2.0f / 3.0f, C1B = 1.0f / 12.0f;
    const float C2A = 4.0f / 3.0f, C2B = -1.0f / 12.0f, C2C = -2.5f;

    for (int t = 0; t < NTT; t++) {
        const int p = t & 1;
        const float* wc  = p ? wf1 : wf0;
        float*       wn  = p ? wf0 : wf1;
        const float* pyr = p ? psiy1 : psiy0;
        float*       pyw = p ? psiy0 : psiy1;
        const float* pxr = p ? psix1 : psix0;
        float*       pxw = p ? psix0 : psix1;

        if (active) {
#pragma unroll
            for (int shot = 0; shot < NSHOT_; shot++) {
                const long o = (long)shot * f;
                const float* wfc = wc + o;

                float wy[9], wx[9];
#pragma unroll
                for (int k = 0; k < 9; k++) wy[k] = wfc[c + (k - 4) * ST];
#pragma unroll
                for (int k = 0; k < 9; k++) wx[k] = (k == 4) ? wy[4] : wfc[c + (k - 4)];

                float d2y = (C2B * (wy[2] + wy[6]) + C2A * (wy[3] + wy[5]) + C2C * wy[4]) * inv_h2;
                float d2x = (C2B * (wx[2] + wx[6]) + C2A * (wx[3] + wx[5]) + C2C * wx[4]) * inv_h2;

                float dwdy[5], dwdx[5];
#pragma unroll
                for (int j = 0; j < 5; j++) {
                    dwdy[j] = (C1A * (wy[j + 3] - wy[j + 1]) - C1B * (wy[j + 4] - wy[j])) * inv_h;
                    dwdx[j] = (C1A * (wx[j + 3] - wx[j + 1]) - C1B * (wx[j + 4] - wx[j])) * inv_h;
                }

                float pny[5], pnx[5];
#pragma unroll
                for (int j = 0; j < 5; j++) {
                    pny[j] = byh[j] * pyr[o + c + (j - 2) * ST] + ayh[j] * dwdy[j];
                    pnx[j] = bxh[j] * pxr[o + c + (j - 2)]      + axh[j] * dwdx[j];
                }

                float dpsiy = (C1A * (pny[3] - pny[1]) - C1B * (pny[4] - pny[0])) * inv_h;
                float dpsix = (C1A * (pnx[3] - pnx[1]) - C1B * (pnx[4] - pnx[0])) * inv_h;

                float zy = byh[2] * zetay_b[o + c] + ayh[2] * (d2y + dpsiy);
                float zx = bxh[2] * zetax_b[o + c] + axh[2] * (d2x + dpsix);

                float lap = d2y + d2x + dpsiy + dpsix + zy + zx;
                float wfp = 2.0f * wy[4] - wn[o + c] + vd * lap;

                // source injection (owner thread), before store & record
                unsigned sm = shot ? sm1 : sm0;
                if (sm) {
#pragma unroll
                    for (int s = 0; s < NSRC_; s++)
                        if (sm & (1u << s)) wfp += vd * amps[(shot * NSRC_ + s) * NTT + t];
                }

                wn[o + c]      = wfp;
                pyw[o + c]     = pny[2];
                pxw[o + c]     = pnx[2];
                zetay_b[o + c] = zy;
                zetax_b[o + c] = zx;

                unsigned long long rm = shot ? rm1 : rm0;
                while (rm) {
                    int r = __ffsll((unsigned long long)rm) - 1;
                    out[(shot * NREC_ + r) * NTT + t] = wfp;
                    rm &= rm - 1;
                }
            }
        }
        grid_barrier(bcnt, bgen, (unsigned)(t + 1));
    }
}

// ---------------- host ----------------
extern "C" void kernel_launch(void* const* d_in, const int* in_sizes, int n_in,
                              void* d_out, int out_size, void* d_ws, size_t ws_size,
                              hipStream_t stream) {
    const float* v      = (const float*)d_in[0];
    const float* amps   = (const float*)d_in[1];
    const int*   srcloc = (const int*)d_in[2];
    const int*   recloc = (const int*)d_in[3];
    float* out = (float*)d_out;

    const long f = (long)ST * ST;
    float* base  = (float*)d_ws;
    float* wf0   = base;             // 2 shots each
    float* wf1   = wf0   + 2 * f;
    float* psiy0 = wf1   + 2 * f;
    float* psiy1 = psiy0 + 2 * f;
    float* psix0 = psiy1 + 2 * f;
    float* psix1 = psix0 + 2 * f;
    float* zetay = psix1 + 2 * f;
    float* zetax = zetay + 2 * f;
    float* v2dt2 = zetax + 2 * f;    // f (shot-independent)
    float* prof  = v2dt2 + f;        // 2*ST
    unsigned* srcmask = (unsigned*)(prof + 2 * ST);                        // 2f uints
    unsigned long long* recmask = (unsigned long long*)(srcmask + 2 * f);  // 2f ull
    unsigned* bar = (unsigned*)(recmask + 2 * f);                          // 64 words

    const long total_words = 23 * f + 2 * ST + 64;  // fields + consts + masks + barrier

    zero_kernel<<<4096, 256, 0, stream>>>(base, total_words);
    populate_kernel<<<(NYP_ * NXP_ + 255) / 256, 256, 0, stream>>>(
        v, srcloc, recloc, v2dt2, prof, srcmask, recmask);

    wave_persistent<<<dim3(NBLK), dim3(NTHR), 0, stream>>>(
        wf0, wf1, psiy0, psiy1, psix0, psix1, zetay, zetax,
        v2dt2, prof, srcmask, recmask, amps, out, bar);
}

// Round 4
// 3071.589 us; speedup vs baseline: 1.0836x; 1.0836x over previous
//
#include <hip/hip_runtime.h>
#include <cstdint>

// ---------------- problem constants ----------------
#define NYD   256
#define NXD   256
#define PADC  22            // PML + FD_PAD
#define NYP_  300           // NY + 2*PAD
#define NXP_  300
#define GD    4             // guard ring width in the global halo arrays
#define ST    308           // global padded stride = NYP_ + 2*GD
#define NTT   250
#define NSHOT_ 2
#define NSRC_  8
#define NREC_  64
#define DT_   0.0005f

// strip decomposition
#define R_     5                     // rows per strip
#define NSTRIP 60                    // strips per shot (60*5 = 300)
#define NBLK   (NSHOT_ * NSTRIP)     // 120 blocks, all co-resident
#define NTHR   512
#define W_     304                   // LDS row width: 300 cols + 2 guard cols each side
#define WFR    (R_ + 8)              // 13 wf rows (radius-4 y-halo)
#define PYR    (R_ + 4)              // 9 psiy rows (radius-2 y-halo)

// ---------------- zero workspace ----------------
__global__ void zero_kernel(float* __restrict__ p, long n) {
    long i = (long)blockIdx.x * blockDim.x + threadIdx.x;
    long stride = (long)gridDim.x * blockDim.x;
    for (; i < n; i += stride) p[i] = 0.0f;
}

// ---------------- one-time setup: v2dt2, PML profiles, src/rec masks ----------------
__global__ void populate_kernel(const float* __restrict__ v,
                                const int* __restrict__ srcloc,
                                const int* __restrict__ recloc,
                                float* __restrict__ v2dt2,
                                float* __restrict__ prof,   // [2*ST]: a, b (guarded)
                                unsigned* __restrict__ srcmask,
                                unsigned long long* __restrict__ recmask) {
    const long f = (long)ST * ST;
    int i = blockIdx.x * 256 + threadIdx.x;

    if (i < NYP_ * NXP_) {
        int y = i / NXP_, x = i % NXP_;
        int vy = min(max(y - PADC, 0), NYD - 1);
        int vx = min(max(x - PADC, 0), NXD - 1);
        float vv = v[vy * NXD + vx];
        v2dt2[(y + GD) * ST + (x + GD)] = vv * vv * (DT_ * DT_);
    }

    if (i < NYP_) {  // DY == DX and NYP == NXP: one profile pair serves both axes
        float fi = (float)i;
        float d = fmaxf(22.0f - fi, fi - 277.0f);
        float frac = fminf(fmaxf(d * (1.0f / 20.0f), 0.0f), 1.0f);
        float sigma_max = 3.0f * 4000.0f * logf(1000.0f) / (2.0f * 20.0f * 5.0f);
        float sigma = sigma_max * frac * frac;
        float alpha = 3.14159265358979323846f * 25.0f * (1.0f - frac);
        float b = expf(-(sigma + alpha) * DT_);
        float a = sigma / (sigma + alpha + 1e-9f) * (b - 1.0f);
        prof[GD + i] = a;        // guard entries stay 0 from zero_kernel
        prof[ST + GD + i] = b;
    }

    if (i < NSHOT_ * NSRC_) {
        int sy = srcloc[2 * i] + PADC;
        int sx = srcloc[2 * i + 1] + PADC;
        int shot = i / NSRC_;
        int s = i % NSRC_;
        atomicOr(&srcmask[shot * f + (long)(sy + GD) * ST + (sx + GD)], 1u << s);
    }

    if (i >= 1024 && i < 1024 + NSHOT_ * NREC_) {
        int j = i - 1024;
        int ry = recloc[2 * j] + PADC;
        int rx = recloc[2 * j + 1] + PADC;
        int shot = j / NREC_;
        int r = j % NREC_;
        atomicOr(&recmask[shot * f + (long)(ry + GD) * ST + (rx + GD)], 1ull << r);
    }
}

// ---------------- software grid barrier (R3-proven) ----------------
__device__ __forceinline__ void grid_barrier(unsigned* cnt, unsigned* gen,
                                             unsigned target) {
    __syncthreads();
    if (threadIdx.x == 0) {
        __threadfence();                               // release (cheap: L2 ~clean now)
        unsigned arrived = atomicAdd(cnt, 1u) + 1u;
        if (arrived == (unsigned)NBLK * target) {
            atomicAdd(gen, 1u);
        } else {
            while (atomicAdd(gen, 0u) < target) __builtin_amdgcn_s_sleep(1);
        }
        __threadfence();                               // acquire
    }
    __syncthreads();
}

// ---------------- persistent time loop, LDS-resident strips ----------------
// Each block owns a 5-row x 300-col strip of one shot. All state (wf x2, psiy,
// psix, zetay, zetax) lives in LDS; only halo rows (wf radius 4, psiy radius 2)
// cross blocks via ping-ponged global buffers. Per step: halo-in, phase A (psi
// update incl. recomputing psiy at the 2 halo rows each side), phase B
// (zeta/wf update + src/rec), halo-out, grid barrier. psix needs no y-halo
// (x-derivative only); zeta is self-coupled. Guard cols/rows stay zero,
// matching the reference's zero-padded FD.
__global__ __launch_bounds__(NTHR) void wave_persistent(
    float* __restrict__ gwf,      // [2 bufs][2 shots][ST*ST] halo exchange (wf)
    float* __restrict__ gpsiy,    // [2 bufs][2 shots][ST*ST] halo exchange (psiy)
    const float* __restrict__ v2dt2,
    const float* __restrict__ prof,
    const unsigned* __restrict__ srcmask,
    const unsigned long long* __restrict__ recmask,
    const float* __restrict__ amps,    // [NSHOT][NSRC][NT]
    float* __restrict__ out,           // [NSHOT][NREC][NT]
    unsigned* bar)
{
    __shared__ float lwf[2][WFR][W_];   // ping-pong wavefield (rows y0-4 .. y0+R+3)
    __shared__ float lpsiy[PYR][W_];    // rows y0-2 .. y0+R+1 (in-place update)
    __shared__ float lpsix[R_][W_];     // owned rows (in-place)
    __shared__ float lzy[R_][W_];
    __shared__ float lzx[R_][W_];
    __shared__ float la[ST], lb[ST];    // PML a/b profile (shared y/x axis)

    const int tid  = threadIdx.x;
    const int shot = blockIdx.x / NSTRIP;
    const int strip= blockIdx.x % NSTRIP;
    const int y0   = strip * R_;
    const long f   = (long)ST * ST;

    // ---- init LDS to zero, load profile ----
    for (int i = tid; i < 2 * WFR * W_; i += NTHR) ((float*)lwf)[i] = 0.0f;
    for (int i = tid; i < PYR * W_;     i += NTHR) ((float*)lpsiy)[i] = 0.0f;
    for (int i = tid; i < R_ * W_;      i += NTHR) {
        ((float*)lpsix)[i] = 0.0f; ((float*)lzy)[i] = 0.0f; ((float*)lzx)[i] = 0.0f;
    }
    for (int i = tid; i < ST; i += NTHR) { la[i] = prof[i]; lb[i] = prof[ST + i]; }

    // ---- per-owned-cell registers (3 cells/thread) ----
    float vdr[3]; unsigned smr[3]; unsigned long long rmr[3];
    int rr[3], col_[3]; bool act[3];
#pragma unroll
    for (int k = 0; k < 3; k++) {
        int i = tid + k * NTHR;
        act[k] = i < R_ * 300;
        int ii = act[k] ? i : 0;
        int r = ii / 300, c = ii % 300;
        rr[k] = r; col_[k] = c + 2;
        long gidx = (long)(GD + y0 + r) * ST + (GD + c);
        vdr[k] = v2dt2[gidx];
        smr[k] = srcmask[shot * f + gidx];
        rmr[k] = recmask[shot * f + gidx];
        if (!act[k]) { smr[k] = 0; rmr[k] = 0; }
    }
    __syncthreads();

    const float inv_h  = 0.2f;    // 1/DY
    const float inv_h2 = 0.04f;   // 1/DY^2
    const float C1A = 2.0f / 3.0f, C1B = 1.0f / 12.0f;
    const float C2A = 4.0f / 3.0f, C2B = -1.0f / 12.0f, C2C = -2.5f;

    for (int t = 0; t < NTT; t++) {
        const int p = t & 1;
        float (*wc)[W_] = lwf[p];        // wfc (state t)
        float (*wm)[W_] = lwf[1 - p];    // wfm (state t-1) -> becomes wfp
        const float* gwr = gwf   + ((long)(t & 1) * NSHOT_ + shot) * f;
        float*       gww = gwf   + ((long)((t + 1) & 1) * NSHOT_ + shot) * f;
        const float* gpr = gpsiy + ((long)(t & 1) * NSHOT_ + shot) * f;
        float*       gpw = gpsiy + ((long)((t + 1) & 1) * NSHOT_ + shot) * f;

        // ---- halo in: wf rows wl {0..3, 9..12}, psiy rows pl {0,1,7,8} ----
        for (int i = tid; i < 8 * W_; i += NTHR) {
            int hr = i / W_, col = i % W_;
            int wl = hr < 4 ? hr : hr + R_;
            int gy = y0 - 4 + wl;
            wc[wl][col] = gwr[(long)(GD + gy) * ST + 2 + col];
        }
        for (int i = tid; i < 4 * W_; i += NTHR) {
            int hr = i / W_, col = i % W_;
            int pl = hr < 2 ? hr : hr + R_;
            int gy = y0 - 2 + pl;
            lpsiy[pl][col] = gpr[(long)(GD + gy) * ST + 2 + col];
        }
        __syncthreads();

        // ---- phase A: psi updates (self-read -> in-place is race-free) ----
        // psiy over owned + 2 halo rows each side (needed by dpsiydy in phase B)
        for (int i = tid; i < PYR * 300; i += NTHR) {
            int pr = i / 300, c = i % 300, col = c + 2;
            int wl = pr + 2;
            float dwdy = (C1A * (wc[wl + 1][col] - wc[wl - 1][col])
                        - C1B * (wc[wl + 2][col] - wc[wl - 2][col])) * inv_h;
            int ya = GD + (y0 - 2 + pr);       // guard entries a=b=0 -> psiy=0 off-grid
            lpsiy[pr][col] = lb[ya] * lpsiy[pr][col] + la[ya] * dwdy;
        }
        // psix over owned rows (x-derivative: no y-halo needed)
        for (int i = tid; i < R_ * 300; i += NTHR) {
            int r = i / 300, c = i % 300, col = c + 2;
            int wl = r + 4;
            float dwdx = (C1A * (wc[wl][col + 1] - wc[wl][col - 1])
                        - C1B * (wc[wl][col + 2] - wc[wl][col - 2])) * inv_h;
            int xa = col + 2;                  // GD + c
            lpsix[r][col] = lb[xa] * lpsix[r][col] + la[xa] * dwdx;
        }
        __syncthreads();

        // ---- phase B: zeta + wavefield update, src inject, halo out, record ----
#pragma unroll
        for (int k = 0; k < 3; k++) if (act[k]) {
            int r = rr[k], col = col_[k];
            int wl = r + 4, pl = r + 2;
            float w0 = wc[wl][col];
            float d2y = (C2B * (wc[wl - 2][col] + wc[wl + 2][col])
                       + C2A * (wc[wl - 1][col] + wc[wl + 1][col]) + C2C * w0) * inv_h2;
            float d2x = (C2B * (wc[wl][col - 2] + wc[wl][col + 2])
                       + C2A * (wc[wl][col - 1] + wc[wl][col + 1]) + C2C * w0) * inv_h2;
            float dpsiy = (C1A * (lpsiy[pl + 1][col] - lpsiy[pl - 1][col])
                         - C1B * (lpsiy[pl + 2][col] - lpsiy[pl - 2][col])) * inv_h;
            float dpsix = (C1A * (lpsix[r][col + 1] - lpsix[r][col - 1])
                         - C1B * (lpsix[r][col + 2] - lpsix[r][col - 2])) * inv_h;
            int ya = GD + y0 + r, xa = col + 2;
            float zy = lb[ya] * lzy[r][col] + la[ya] * (d2y + dpsiy);
            float zx = lb[xa] * lzx[r][col] + la[xa] * (d2x + dpsix);
            lzy[r][col] = zy; lzx[r][col] = zx;
            float lap = d2y + d2x + dpsiy + dpsix + zy + zx;
            float wfp = 2.0f * w0 - wm[wl][col] + vdr[k] * lap;

            unsigned sm = smr[k];
            if (sm) {
#pragma unroll
                for (int s = 0; s < NSRC_; s++)
                    if (sm & (1u << s)) wfp += vdr[k] * amps[(shot * NSRC_ + s) * NTT + t];
            }
            wm[wl][col] = wfp;   // in-place: wfm slot becomes wfp

            long gidx = (long)(GD + y0 + r) * ST + 2 + col;
            gww[gidx] = wfp;                                   // all 5 rows are edge rows
            if (r < 2 || r >= R_ - 2) gpw[gidx] = lpsiy[pl][col];  // rows {0,1,3,4}

            unsigned long long rm = rmr[k];
            while (rm) {
                int rec = __ffsll(rm) - 1;
                out[(shot * NREC_ + rec) * NTT + t] = wfp;
                rm &= rm - 1;
            }
        }

        grid_barrier(bar, bar + 32, (unsigned)(t + 1));
    }
}

// ---------------- host ----------------
extern "C" void kernel_launch(void* const* d_in, const int* in_sizes, int n_in,
                              void* d_out, int out_size, void* d_ws, size_t ws_size,
                              hipStream_t stream) {
    const float* v      = (const float*)d_in[0];
    const float* amps   = (const float*)d_in[1];
    const int*   srcloc = (const int*)d_in[2];
    const int*   recloc = (const int*)d_in[3];
    float* out = (float*)d_out;

    const long f = (long)ST * ST;
    float* base   = (float*)d_ws;
    float* gwf    = base;              // 2 bufs x 2 shots = 4f
    float* gpsiy  = gwf + 4 * f;       // 4f
    float* v2dt2  = gpsiy + 4 * f;     // f
    float* prof   = v2dt2 + f;         // 2*ST
    unsigned* srcmask = (unsigned*)(prof + 2 * ST);                        // 2f
    unsigned long long* recmask = (unsigned long long*)(srcmask + 2 * f);  // 4f words
    unsigned* bar = (unsigned*)(recmask + 2 * f);                          // 64 words

    const long total_words = 15 * f + 2 * ST + 64;

    zero_kernel<<<4096, 256, 0, stream>>>(base, total_words);
    populate_kernel<<<(NYP_ * NXP_ + 255) / 256, 256, 0, stream>>>(
        v, srcloc, recloc, v2dt2, prof, srcmask, recmask);

    wave_persistent<<<dim3(NBLK), dim3(NTHR), 0, stream>>>(
        gwf, gpsiy, v2dt2, prof, srcmask, recmask, amps, out, bar);
}